// Round 7
// baseline (1012.314 us; speedup 1.0000x reference)
//
#include <hip/hip_runtime.h>
#include <stdint.h>

// Poisson spike encoding, bit-exact vs JAX CPU reference (verified rounds 2-5).
// Round 7: ILP-2 (two independent Knuth streams per lane, 13+12 chunk split)
// with the round-6 bug fixed: stream RNG state (S, d, keys) is re-initialized
// at every chunk start, wiping the garbage that frozen-stream draws accumulate
// while the sibling stream finishes.

#define TWIN 500
#define HALF 250
#define WARM 26          // cummax carry distance; P(count>=26) ~ 1e-18 dataset-wide
#define CHUNK 25         // elements per flush
#define SPLIT 13         // stream A: [base, base+13); stream B: [base+13, base+25)
#define NKEYS 32         // subkey table; d+1 <= DCAP+1 = 31 < 32 always in-range
#define DCAP 30          // hard safety cap, unreachable on this input

struct Subkeys {
  uint32_t a[NKEYS];
  uint32_t b[NKEYS];
};

__host__ __device__ __forceinline__ uint32_t rotl32(uint32_t x, uint32_t r) {
#if defined(__HIP_DEVICE_COMPILE__) && __has_builtin(__builtin_amdgcn_alignbit)
  return __builtin_amdgcn_alignbit(x, x, 32u - r);   // 1 VALU op
#else
  return (x << r) | (x >> (32u - r));
#endif
}

__host__ __device__ __forceinline__ void tf2x32(uint32_t k0, uint32_t k1,
                                                uint32_t x0, uint32_t x1,
                                                uint32_t& o0, uint32_t& o1) {
  const uint32_t ks2 = k0 ^ k1 ^ 0x1BD11BDAu;
  x0 += k0; x1 += k1;
#define TF_RND(r) { x0 += x1; x1 = rotl32(x1, (r)); x1 ^= x0; }
  TF_RND(13) TF_RND(15) TF_RND(26) TF_RND(6)
  x0 += k1;  x1 += ks2 + 1u;
  TF_RND(17) TF_RND(29) TF_RND(16) TF_RND(24)
  x0 += ks2; x1 += k0 + 2u;
  TF_RND(13) TF_RND(15) TF_RND(26) TF_RND(6)
  x0 += k0;  x1 += k1 + 3u;
  TF_RND(17) TF_RND(29) TF_RND(16) TF_RND(24)
  x0 += k1;  x1 += ks2 + 4u;
  TF_RND(13) TF_RND(15) TF_RND(26) TF_RND(6)
  x0 += ks2; x1 += k0 + 5u;
#undef TF_RND
  o0 = x0; o1 = x1;
}

// Cephes/Eigen plog<float>, FMA-contracted exactly as bit-verified in round 2.
__device__ __forceinline__ float cephes_logf(float u) {
  float x = fmaxf(u, __uint_as_float(0x00800000u));
  int emm0 = (int)(__float_as_uint(x) >> 23);
  x = __uint_as_float((__float_as_uint(x) & 0x807FFFFFu) | 0x3F000000u);
  float e = (float)(emm0 - 127) + 1.0f;
  const bool mask = x < 0.707106781186547524f;
  float tmp = mask ? x : 0.0f;
  x = x - 1.0f;
  e = e - (mask ? 1.0f : 0.0f);
  x = x + tmp;
  float z = x * x;
  float y = 7.0376836292E-2f;
  y = fmaf(y, x, -1.1514610310E-1f);
  y = fmaf(y, x,  1.1676998740E-1f);
  y = fmaf(y, x, -1.2420140846E-1f);
  y = fmaf(y, x,  1.4249322787E-1f);
  y = fmaf(y, x, -1.6668057665E-1f);
  y = fmaf(y, x,  2.0000714765E-1f);
  y = fmaf(y, x, -2.4999993993E-1f);
  y = fmaf(y, x,  3.3333331174E-1f);
  y = y * x;
  y = y * z;
  y = fmaf(e, -2.12194440e-4f, y);
  y = fmaf(z, -0.5f, y);
  x = x + y;
  x = fmaf(e, 0.693359375f, x);
  return x;
}

// One Knuth draw for one stream. Frozen streams (j>=lim) keep drawing with
// garbage S/d/keys; all VISIBLE updates (ce, j, runm, bits) are act-guarded or
// idempotent, and the garbage hidden state is wiped at the next chunk start.
#define STEP(ka, kb, S, ce, d, j, runm, lim, REC)                           \
  {                                                                         \
    const bool act = (j < (lim));                                           \
    const uint2 nk = lk[(uint32_t)(d + 1)];                                 \
    const uint32_t ks2 = ka ^ kb ^ 0x1BD11BDAu;                             \
    uint32_t t0 = ka;                                                       \
    uint32_t t1 = e_row + (uint32_t)j + kb;                                 \
    t0 += t1; t1 = rotl32(t1, 13); t1 ^= t0;                                \
    t0 += t1; t1 = rotl32(t1, 15); t1 ^= t0;                                \
    t0 += t1; t1 = rotl32(t1, 26); t1 ^= t0;                                \
    t0 += t1; t1 = rotl32(t1,  6); t1 ^= t0;                                \
    t0 += kb; t1 += ks2 + 1u;                                               \
    t0 += t1; t1 = rotl32(t1, 17); t1 ^= t0;                                \
    t0 += t1; t1 = rotl32(t1, 29); t1 ^= t0;                                \
    t0 += t1; t1 = rotl32(t1, 16); t1 ^= t0;                                \
    t0 += t1; t1 = rotl32(t1, 24); t1 ^= t0;                                \
    t0 += ks2; t1 += ka + 2u;                                               \
    t0 += t1; t1 = rotl32(t1, 13); t1 ^= t0;                                \
    t0 += t1; t1 = rotl32(t1, 15); t1 ^= t0;                                \
    t0 += t1; t1 = rotl32(t1, 26); t1 ^= t0;                                \
    t0 += t1; t1 = rotl32(t1,  6); t1 ^= t0;                                \
    t0 += ka; t1 += kb + 3u;                                                \
    t0 += t1; t1 = rotl32(t1, 17); t1 ^= t0;                                \
    t0 += t1; t1 = rotl32(t1, 29); t1 ^= t0;                                \
    t0 += t1; t1 = rotl32(t1, 16); t1 ^= t0;                                \
    t0 += t1; t1 = rotl32(t1, 24); t1 ^= t0;                                \
    t0 += kb; t1 += ks2 + 4u;                                               \
    t0 += t1; t1 = rotl32(t1, 13); t1 ^= t0;                                \
    t0 += t1; t1 = rotl32(t1, 15); t1 ^= t0;                                \
    t0 += t1; t1 = rotl32(t1, 26); t1 ^= t0;                                \
    t0 += t1; t1 = rotl32(t1,  6); t1 ^= t0;                                \
    t0 += ks2; t1 += ka + 5u;                                               \
    const uint32_t rb = t0 ^ t1;                                            \
    const float u = __uint_as_float((rb >> 9) | 0x3F800000u) - 1.0f;        \
    S += cephes_logf(u);                                                    \
    const bool alive = S > neg_lam;                                         \
    const bool fin = (!alive) || (d >= DCAP);                               \
    ce += (alive && act) ? 1 : 0;                                           \
    runm = runm > ce ? runm : ce;                                           \
    REC                                                                     \
    S  = fin ? 0.0f : S;                                                    \
    d  = fin ? 0 : d + 1;                                                   \
    ka = fin ? k0a : nk.x;                                                  \
    kb = fin ? k0b : nk.y;                                                  \
    j += (fin && act) ? 1 : 0;                                              \
    ce = fin ? j : ce;                                                      \
  }

// Fresh-element RNG state for both streams (start of every chunk / warmup).
#define RESET_STREAMS()                                                     \
  SA = 0.0f; SB = 0.0f; dA = 0; dB = 0;                                     \
  kaA = k0a; kbA = k0b; kaB = k0a; kbB = k0b;

__global__ void CustomPoisson_12292196401945_kernel(
    const float* __restrict__ img, int* __restrict__ out,
    Subkeys sk, int N) {
  __shared__ uint2 lk[NKEYS];
  if (threadIdx.x < NKEYS) {
    lk[threadIdx.x] = make_uint2(sk.a[threadIdx.x], sk.b[threadIdx.x]);
  }
  __syncthreads();

  const int tid = blockIdx.x * blockDim.x + threadIdx.x;
  const int i = (tid >= N) ? (tid - N) : tid;       // pixel
  const int h = (tid >= N) ? 1 : 0;                 // row half (wave-uniform)
  const float neg_lam = -img[i];
  const uint32_t k0a = sk.a[0], k0b = sk.b[0];      // uniform -> SGPRs
  const uint32_t e_row = (uint32_t)i * TWIN;

  const int jstart = h ? HALF : 0;
  const int jend = jstart + HALF;

  // Two independent stream states (A and B)
  float SA, SB;
  int dA, dB;
  uint32_t kaA, kbA, kaB, kbB;
  int jA, jB, ceA, ceB;
  int R0 = 0;                        // cummax carry across chunks

  if (h) {
    // Warmup [js-26, js): A=[js-26,js-13), B=[js-13,js); carry only (no bits).
    RESET_STREAMS()
    int rA = 0, rB = 0;
    jA = jstart - WARM; jB = jstart - SPLIT;
    ceA = jA; ceB = jB;
    const int lA = jstart - SPLIT, lB = jstart;
    while (__any((jA < lA) | (jB < lB))) {
      STEP(kaA, kbA, SA, ceA, dA, jA, rA, lA, )
      STEP(kaB, kbB, SB, ceB, dB, jB, rB, lB, )
    }
    R0 = rA > rB ? rA : rB;
  }

  uint32_t off = (uint32_t)jstart * (uint32_t)N + (uint32_t)i;  // fits 32b
  for (int base = jstart; base < jend; base += CHUNK) {
    RESET_STREAMS()                  // wipe frozen-draw garbage (round-6 bug)
    uint32_t bits = 0;
    int rA = R0, rB = R0;
    jA = base;         jB = base + SPLIT;
    ceA = jA;          ceB = jB;
    const int lA = base + SPLIT, lB = base + CHUNK;

    while (__any((jA < lA) | (jB < lB))) {
      STEP(kaA, kbA, SA, ceA, dA, jA, rA, lA,
           bits |= (uint32_t)((rA > jA) ? 1u : 0u) << (uint32_t)(jA - base);)
      STEP(kaB, kbB, SB, ceB, dB, jB, rB, lB,
           bits |= (uint32_t)((rB > jB) ? 1u : 0u) << (uint32_t)(jB - base);)
    }

    // Patch B's bits with stream A's final cummax (contiguous low range):
    // position p in [SPLIT, CHUNK) spikes iff base+p < rA.
    int thr = rA - base;
    thr = thr < SPLIT ? SPLIT : thr;
    thr = thr > CHUNK ? CHUNK : thr;
    bits |= ((1u << (uint32_t)thr) - 1u) & ~((1u << SPLIT) - 1u);

    R0 = rA > rB ? rA : rB;

    // Coalesced flush: lane writes its column for rows [base, base+CHUNK).
    #pragma unroll 1
    for (int t = 0; t < CHUNK; ++t) {
      out[off] = (int)((bits >> t) & 1u);
      off += (uint32_t)N;
    }
  }
}

extern "C" void kernel_launch(void* const* d_in, const int* in_sizes, int n_in,
                              void* d_out, int out_size, void* d_ws, size_t ws_size,
                              hipStream_t stream) {
  const float* img = (const float*)d_in[0];
  int* out = (int*)d_out;
  const int N = in_sizes[0];  // 262144

  // Host-side subkey chain: rng = (0, 42); partitionable fold-like split.
  Subkeys sk;
  uint32_t r0 = 0u, r1 = 42u;
  for (int d = 0; d < NKEYS; ++d) {
    uint32_t s0, s1, n0, n1;
    tf2x32(r0, r1, 0u, 1u, s0, s1);  // subkey for draw d
    tf2x32(r0, r1, 0u, 0u, n0, n1);  // next rng
    sk.a[d] = s0; sk.b[d] = s1;
    r0 = n0; r1 = n1;
  }

  dim3 block(256);
  dim3 grid((2 * N + 255) / 256);
  hipLaunchKernelGGL(CustomPoisson_12292196401945_kernel, grid, block, 0, stream,
                     img, out, sk, N);
}

// Round 8
// 740.415 us; speedup vs baseline: 1.3672x; 1.3672x over previous
//
#include <hip/hip_runtime.h>
#include <stdint.h>

// Poisson spike encoding, bit-exact vs JAX CPU reference (verified rounds 2-5).
// Round 8: block-local lambda-sort (bitonic, 1024 jobs) so each wave gets a
// narrow lambda band -> divergence 1.97x -> ~1.5x; unchunked streaming with
// LDS word-exchange for coalesced stores. STEP semantics identical to round 5.

#define TWIN 500
#define HALF 250
#define WARM 26          // cummax carry distance; P(count>=26) ~ 1e-18 dataset-wide
#define NKEYS 32         // subkey table; d+1 <= DCAP+1 = 31 < 32 always in-range
#define DCAP 30          // hard safety cap, unreachable on this input
#define BLOCK 1024
#define XPITCH 9         // exchange pitch in words (9 -> conflict-free reads)

struct Subkeys {
  uint32_t a[NKEYS];
  uint32_t b[NKEYS];
};

__host__ __device__ __forceinline__ uint32_t rotl32(uint32_t x, uint32_t r) {
#if defined(__HIP_DEVICE_COMPILE__) && __has_builtin(__builtin_amdgcn_alignbit)
  return __builtin_amdgcn_alignbit(x, x, 32u - r);   // 1 VALU op
#else
  return (x << r) | (x >> (32u - r));
#endif
}

__host__ __device__ __forceinline__ void tf2x32(uint32_t k0, uint32_t k1,
                                                uint32_t x0, uint32_t x1,
                                                uint32_t& o0, uint32_t& o1) {
  const uint32_t ks2 = k0 ^ k1 ^ 0x1BD11BDAu;
  x0 += k0; x1 += k1;
#define TF_RND(r) { x0 += x1; x1 = rotl32(x1, (r)); x1 ^= x0; }
  TF_RND(13) TF_RND(15) TF_RND(26) TF_RND(6)
  x0 += k1;  x1 += ks2 + 1u;
  TF_RND(17) TF_RND(29) TF_RND(16) TF_RND(24)
  x0 += ks2; x1 += k0 + 2u;
  TF_RND(13) TF_RND(15) TF_RND(26) TF_RND(6)
  x0 += k0;  x1 += k1 + 3u;
  TF_RND(17) TF_RND(29) TF_RND(16) TF_RND(24)
  x0 += k1;  x1 += ks2 + 4u;
  TF_RND(13) TF_RND(15) TF_RND(26) TF_RND(6)
  x0 += ks2; x1 += k0 + 5u;
#undef TF_RND
  o0 = x0; o1 = x1;
}

// Cephes/Eigen plog<float>, FMA-contracted exactly as bit-verified in round 2.
__device__ __forceinline__ float cephes_logf(float u) {
  float x = fmaxf(u, __uint_as_float(0x00800000u));
  int emm0 = (int)(__float_as_uint(x) >> 23);
  x = __uint_as_float((__float_as_uint(x) & 0x807FFFFFu) | 0x3F000000u);
  float e = (float)(emm0 - 127) + 1.0f;
  const bool mask = x < 0.707106781186547524f;
  float tmp = mask ? x : 0.0f;
  x = x - 1.0f;
  e = e - (mask ? 1.0f : 0.0f);
  x = x + tmp;
  float z = x * x;
  float y = 7.0376836292E-2f;
  y = fmaf(y, x, -1.1514610310E-1f);
  y = fmaf(y, x,  1.1676998740E-1f);
  y = fmaf(y, x, -1.2420140846E-1f);
  y = fmaf(y, x,  1.4249322787E-1f);
  y = fmaf(y, x, -1.6668057665E-1f);
  y = fmaf(y, x,  2.0000714765E-1f);
  y = fmaf(y, x, -2.4999993993E-1f);
  y = fmaf(y, x,  3.3333331174E-1f);
  y = y * x;
  y = y * z;
  y = fmaf(e, -2.12194440e-4f, y);
  y = fmaf(z, -0.5f, y);
  x = x + y;
  x = fmaf(e, 0.693359375f, x);
  return x;
}

__global__ __attribute__((amdgpu_flat_work_group_size(BLOCK, BLOCK)))
void CustomPoisson_12292196401945_kernel(
    const float* __restrict__ img, int* __restrict__ out,
    Subkeys sk, int N) {
  __shared__ uint2 lk[NKEYS];
  __shared__ unsigned long long sbuf[BLOCK];       // sort records
  __shared__ uint32_t xbuf[BLOCK * XPITCH];        // spike-word exchange

  const int tid = threadIdx.x;
  if (tid < NKEYS) lk[tid] = make_uint2(sk.a[tid], sk.b[tid]);

  const int hb = N / BLOCK;                // blocks per half (256)
  const int b = blockIdx.x;
  const int h = (b >= hb) ? 1 : 0;         // block-uniform row half
  const int pixBase = (b - h * hb) * BLOCK;

  // ---- one-time bitonic sort of (lambda, local job id), ascending ----
  // Output correctness needs only bijectivity (swap-based => guaranteed);
  // sort quality affects only divergence.
  {
    const float lam0 = img[pixBase + tid];
    sbuf[tid] = ((unsigned long long)__float_as_uint(lam0) << 32) | (uint32_t)tid;
  }
  __syncthreads();
  for (int ks = 2; ks <= BLOCK; ks <<= 1) {
    for (int js = ks >> 1; js > 0; js >>= 1) {
      const int p = tid ^ js;
      if (p > tid) {
        const bool up = ((tid & ks) == 0);
        const unsigned long long a = sbuf[tid], c = sbuf[p];
        const bool sw = up ? (a > c) : (a < c);
        if (sw) { sbuf[tid] = c; sbuf[p] = a; }
      }
      __syncthreads();
    }
  }
  const unsigned long long rec = sbuf[tid];        // rank tid's record
  const uint32_t orig = (uint32_t)rec;             // original local job id
  const float neg_lam = -__uint_as_float((uint32_t)(rec >> 32));

  const uint32_t k0a = sk.a[0], k0b = sk.b[0];     // uniform -> SGPRs
  const int jstart = h ? HALF : 0;
  const uint32_t e_base =
      (uint32_t)(pixBase + (int)orig) * TWIN + (uint32_t)jstart;

  // ---- unchunked streaming of this job's 250-step half ----
  int jj = h ? -WARM : 0;      // relative step; record only jj>=0
  float S = 0.0f;
  int k = 0, d = 0;
  uint32_t cka = k0a, ckb = k0b;
  int runmax = 0;              // absolute-ends cummax (warmup j_abs>=224: safe)
  uint32_t cur = 0;            // current 32-step spike word

  while (__any(jj < HALF)) {
    if (jj < HALF) {
      const uint2 nk = lk[(uint32_t)(d + 1)];      // prefetch next subkey
      const uint32_t ks2 = cka ^ ckb ^ 0x1BD11BDAu;
      uint32_t t0 = cka;                           // x0 = 0 + k0
      uint32_t t1 = e_base + (uint32_t)jj + ckb;   // x1 = e + k1
      t0 += t1; t1 = rotl32(t1, 13); t1 ^= t0;
      t0 += t1; t1 = rotl32(t1, 15); t1 ^= t0;
      t0 += t1; t1 = rotl32(t1, 26); t1 ^= t0;
      t0 += t1; t1 = rotl32(t1,  6); t1 ^= t0;
      t0 += ckb; t1 += ks2 + 1u;
      t0 += t1; t1 = rotl32(t1, 17); t1 ^= t0;
      t0 += t1; t1 = rotl32(t1, 29); t1 ^= t0;
      t0 += t1; t1 = rotl32(t1, 16); t1 ^= t0;
      t0 += t1; t1 = rotl32(t1, 24); t1 ^= t0;
      t0 += ks2; t1 += cka + 2u;
      t0 += t1; t1 = rotl32(t1, 13); t1 ^= t0;
      t0 += t1; t1 = rotl32(t1, 15); t1 ^= t0;
      t0 += t1; t1 = rotl32(t1, 26); t1 ^= t0;
      t0 += t1; t1 = rotl32(t1,  6); t1 ^= t0;
      t0 += cka; t1 += ckb + 3u;
      t0 += t1; t1 = rotl32(t1, 17); t1 ^= t0;
      t0 += t1; t1 = rotl32(t1, 29); t1 ^= t0;
      t0 += t1; t1 = rotl32(t1, 16); t1 ^= t0;
      t0 += t1; t1 = rotl32(t1, 24); t1 ^= t0;
      t0 += ckb; t1 += ks2 + 4u;
      t0 += t1; t1 = rotl32(t1, 13); t1 ^= t0;
      t0 += t1; t1 = rotl32(t1, 15); t1 ^= t0;
      t0 += t1; t1 = rotl32(t1, 26); t1 ^= t0;
      t0 += t1; t1 = rotl32(t1,  6); t1 ^= t0;
      t0 += ks2; t1 += cka + 5u;
      const uint32_t rb = t0 ^ t1;
      const float u = __uint_as_float((rb >> 9) | 0x3F800000u) - 1.0f;
      S += cephes_logf(u);
      const bool alive = S > neg_lam;
      const int k2 = k + (alive ? 1 : 0);
      const bool fin = (!alive) || (d >= DCAP);
      const int ends = k2 + jstart + jj;
      runmax = runmax > ends ? runmax : ends;      // idempotent (monotone)
      const bool recb = fin && (jj >= 0);
      const uint32_t bit =
          (uint32_t)((runmax > jstart + jj) ? 1u : 0u) << ((uint32_t)jj & 31u);
      cur |= recb ? bit : 0u;
      const bool flush = recb && (((jj & 31) == 31) || (jj == HALF - 1));
      if (flush) xbuf[orig * XPITCH + (uint32_t)(jj >> 5)] = cur;
      cur = flush ? 0u : cur;
      S = fin ? 0.0f : S;
      k = fin ? 0 : k2;
      d = fin ? 0 : d + 1;
      cka = fin ? k0a : nk.x;
      ckb = fin ? k0b : nk.y;
      jj += fin ? 1 : 0;
    }
  }
  __syncthreads();

  // ---- coalesced unpack: thread t stores original job t (pixel pixBase+t) ----
  uint32_t off = (uint32_t)jstart * (uint32_t)N + (uint32_t)(pixBase + tid);
  for (int w = 0; w < 8; ++w) {
    const uint32_t word = xbuf[tid * XPITCH + w];
    const int nb = (w < 7) ? 32 : (HALF - 7 * 32);   // 26 bits in last word
    #pragma unroll 1
    for (int t2 = 0; t2 < nb; ++t2) {
      out[off] = (int)((word >> t2) & 1u);
      off += (uint32_t)N;
    }
  }
}

extern "C" void kernel_launch(void* const* d_in, const int* in_sizes, int n_in,
                              void* d_out, int out_size, void* d_ws, size_t ws_size,
                              hipStream_t stream) {
  const float* img = (const float*)d_in[0];
  int* out = (int*)d_out;
  const int N = in_sizes[0];  // 262144 (multiple of BLOCK)

  // Host-side subkey chain: rng = (0, 42); partitionable fold-like split.
  Subkeys sk;
  uint32_t r0 = 0u, r1 = 42u;
  for (int d = 0; d < NKEYS; ++d) {
    uint32_t s0, s1, n0, n1;
    tf2x32(r0, r1, 0u, 1u, s0, s1);  // subkey for draw d
    tf2x32(r0, r1, 0u, 0u, n0, n1);  // next rng
    sk.a[d] = s0; sk.b[d] = s1;
    r0 = n0; r1 = n1;
  }

  dim3 block(BLOCK);
  dim3 grid(2 * (N / BLOCK));
  hipLaunchKernelGGL(CustomPoisson_12292196401945_kernel, grid, block, 0, stream,
                     img, out, sk, N);
}

// Round 9
// 702.619 us; speedup vs baseline: 1.4408x; 1.0538x over previous
//
#include <hip/hip_runtime.h>
#include <stdint.h>

// Poisson spike encoding, bit-exact vs JAX CPU reference (verified rounds 2-8).
// Round 9: slimmed draw loop — no DCAP (P~1e-34), single alive-mask state
// swaps, relative indexing, unconditional bit-record + LDS word flush
// (both provably idempotent), 2 draws per ballot. Structure = round 8.

#define TWIN 500
#define HALF 250
#define WARM 26          // cummax carry distance; P(count>=26) ~ 1e-18 dataset-wide
#define NKEYS 32         // subkey table; draws beyond ~15 unreachable
#define BLOCK 1024
#define XPITCH 9         // exchange pitch in words (conflict-spreading)

struct Subkeys {
  uint32_t a[NKEYS];
  uint32_t b[NKEYS];
};

__host__ __device__ __forceinline__ uint32_t rotl32(uint32_t x, uint32_t r) {
#if defined(__HIP_DEVICE_COMPILE__) && __has_builtin(__builtin_amdgcn_alignbit)
  return __builtin_amdgcn_alignbit(x, x, 32u - r);   // 1 VALU op
#else
  return (x << r) | (x >> (32u - r));
#endif
}

__host__ __device__ __forceinline__ void tf2x32(uint32_t k0, uint32_t k1,
                                                uint32_t x0, uint32_t x1,
                                                uint32_t& o0, uint32_t& o1) {
  const uint32_t ks2 = k0 ^ k1 ^ 0x1BD11BDAu;
  x0 += k0; x1 += k1;
#define TF_RND(r) { x0 += x1; x1 = rotl32(x1, (r)); x1 ^= x0; }
  TF_RND(13) TF_RND(15) TF_RND(26) TF_RND(6)
  x0 += k1;  x1 += ks2 + 1u;
  TF_RND(17) TF_RND(29) TF_RND(16) TF_RND(24)
  x0 += ks2; x1 += k0 + 2u;
  TF_RND(13) TF_RND(15) TF_RND(26) TF_RND(6)
  x0 += k0;  x1 += k1 + 3u;
  TF_RND(17) TF_RND(29) TF_RND(16) TF_RND(24)
  x0 += k1;  x1 += ks2 + 4u;
  TF_RND(13) TF_RND(15) TF_RND(26) TF_RND(6)
  x0 += ks2; x1 += k0 + 5u;
#undef TF_RND
  o0 = x0; o1 = x1;
}

// Cephes/Eigen plog<float>, FMA-contracted exactly as bit-verified in round 2.
__device__ __forceinline__ float cephes_logf(float u) {
  float x = fmaxf(u, __uint_as_float(0x00800000u));
  int emm0 = (int)(__float_as_uint(x) >> 23);
  x = __uint_as_float((__float_as_uint(x) & 0x807FFFFFu) | 0x3F000000u);
  float e = (float)(emm0 - 127) + 1.0f;
  const bool mask = x < 0.707106781186547524f;
  float tmp = mask ? x : 0.0f;
  x = x - 1.0f;
  e = e - (mask ? 1.0f : 0.0f);
  x = x + tmp;
  float z = x * x;
  float y = 7.0376836292E-2f;
  y = fmaf(y, x, -1.1514610310E-1f);
  y = fmaf(y, x,  1.1676998740E-1f);
  y = fmaf(y, x, -1.2420140846E-1f);
  y = fmaf(y, x,  1.4249322787E-1f);
  y = fmaf(y, x, -1.6668057665E-1f);
  y = fmaf(y, x,  2.0000714765E-1f);
  y = fmaf(y, x, -2.4999993993E-1f);
  y = fmaf(y, x,  3.3333331174E-1f);
  y = y * x;
  y = y * z;
  y = fmaf(e, -2.12194440e-4f, y);
  y = fmaf(z, -0.5f, y);
  x = x + y;
  x = fmaf(e, 0.693359375f, x);
  return x;
}

// One Knuth draw. Relative indexing (jj, ce, runm all relative to jstart).
// fin == !alive (DCAP dropped: P(31 survivals) ~ 1e-34 per element).
// DO_REC: record spike bit + flush word to LDS (both idempotent, ungated).
#define DRAW(DO_REC)                                                        \
  {                                                                         \
    const uint2 nk = lk[(uint32_t)(d + 1)];                                 \
    const uint32_t ks2 = cka ^ ckb ^ 0x1BD11BDAu;                           \
    uint32_t t0 = cka;                           /* x0 = 0 + k0 */          \
    uint32_t t1 = e_base + (uint32_t)jj + ckb;   /* x1 = e + k1 */          \
    t0 += t1; t1 = rotl32(t1, 13); t1 ^= t0;                                \
    t0 += t1; t1 = rotl32(t1, 15); t1 ^= t0;                                \
    t0 += t1; t1 = rotl32(t1, 26); t1 ^= t0;                                \
    t0 += t1; t1 = rotl32(t1,  6); t1 ^= t0;                                \
    t0 += ckb; t1 += ks2 + 1u;                                              \
    t0 += t1; t1 = rotl32(t1, 17); t1 ^= t0;                                \
    t0 += t1; t1 = rotl32(t1, 29); t1 ^= t0;                                \
    t0 += t1; t1 = rotl32(t1, 16); t1 ^= t0;                                \
    t0 += t1; t1 = rotl32(t1, 24); t1 ^= t0;                                \
    t0 += ks2; t1 += cka + 2u;                                              \
    t0 += t1; t1 = rotl32(t1, 13); t1 ^= t0;                                \
    t0 += t1; t1 = rotl32(t1, 15); t1 ^= t0;                                \
    t0 += t1; t1 = rotl32(t1, 26); t1 ^= t0;                                \
    t0 += t1; t1 = rotl32(t1,  6); t1 ^= t0;                                \
    t0 += cka; t1 += ckb + 3u;                                              \
    t0 += t1; t1 = rotl32(t1, 17); t1 ^= t0;                                \
    t0 += t1; t1 = rotl32(t1, 29); t1 ^= t0;                                \
    t0 += t1; t1 = rotl32(t1, 16); t1 ^= t0;                                \
    t0 += t1; t1 = rotl32(t1, 24); t1 ^= t0;                                \
    t0 += ckb; t1 += ks2 + 4u;                                              \
    t0 += t1; t1 = rotl32(t1, 13); t1 ^= t0;                                \
    t0 += t1; t1 = rotl32(t1, 15); t1 ^= t0;                                \
    t0 += t1; t1 = rotl32(t1, 26); t1 ^= t0;                                \
    t0 += t1; t1 = rotl32(t1,  6); t1 ^= t0;                                \
    t0 += ks2; t1 += cka + 5u;                                              \
    const uint32_t rb = t0 ^ t1;                                            \
    const float u = __uint_as_float((rb >> 9) | 0x3F800000u) - 1.0f;        \
    S += cephes_logf(u);                                                    \
    const bool alive = S > neg_lam;                                         \
    const int tnx = jj + 1;                                                 \
    const int ce_eff = ce + (alive ? 1 : 0);     /* end if alive */         \
    runm = runm > ce_eff ? runm : ce_eff;        /* monotone, idempotent */ \
    if (DO_REC) {                                                           \
      cur |= (runm > jj) ? (1u << ((uint32_t)jj & 31u)) : 0u;               \
      xbuf[xw_base + ((uint32_t)jj >> 5)] = cur; /* idempotent rewrite */   \
    }                                                                       \
    S   = alive ? S : 0.0f;                                                 \
    d   = alive ? d + 1 : 0;                                                \
    cka = alive ? nk.x : k0a;                                               \
    ckb = alive ? nk.y : k0b;                                               \
    ce  = alive ? ce_eff : tnx;                                             \
    jj  = alive ? jj : tnx;                                                 \
    if (DO_REC) cur = (!alive && ((tnx & 31) == 0)) ? 0u : cur;             \
  }

__global__ __attribute__((amdgpu_flat_work_group_size(BLOCK, BLOCK)))
void CustomPoisson_12292196401945_kernel(
    const float* __restrict__ img, int* __restrict__ out,
    Subkeys sk, int N) {
  __shared__ uint2 lk[NKEYS];
  __shared__ unsigned long long sbuf[BLOCK];       // sort records
  __shared__ uint32_t xbuf[BLOCK * XPITCH];        // spike-word exchange

  const int tid = threadIdx.x;
  if (tid < NKEYS) lk[tid] = make_uint2(sk.a[tid], sk.b[tid]);

  const int hb = N / BLOCK;                // blocks per half (256)
  const int b = blockIdx.x;
  const int h = (b >= hb) ? 1 : 0;         // block-uniform row half
  const int pixBase = (b - h * hb) * BLOCK;

  // ---- one-time bitonic sort of (lambda, local job id), ascending ----
  // Correctness needs only bijectivity (swap-based => guaranteed).
  {
    const float lam0 = img[pixBase + tid];
    sbuf[tid] = ((unsigned long long)__float_as_uint(lam0) << 32) | (uint32_t)tid;
  }
  __syncthreads();
  for (int ks = 2; ks <= BLOCK; ks <<= 1) {
    for (int js = ks >> 1; js > 0; js >>= 1) {
      const int p = tid ^ js;
      if (p > tid) {
        const bool up = ((tid & ks) == 0);
        const unsigned long long a = sbuf[tid], c = sbuf[p];
        const bool sw = up ? (a > c) : (a < c);
        if (sw) { sbuf[tid] = c; sbuf[p] = a; }
      }
      __syncthreads();
    }
  }
  const unsigned long long rec = sbuf[tid];        // rank tid's record
  const uint32_t orig = (uint32_t)rec;             // original local job id
  const float neg_lam = -__uint_as_float((uint32_t)(rec >> 32));

  const uint32_t k0a = sk.a[0], k0b = sk.b[0];     // uniform -> SGPRs
  const int jstart = h ? HALF : 0;
  const uint32_t e_base =
      (uint32_t)(pixBase + (int)orig) * TWIN + (uint32_t)jstart;
  const uint32_t xw_base = orig * XPITCH;

  // ---- streaming state (all step indices relative to jstart) ----
  int jj = h ? -WARM : 0;
  float S = 0.0f;
  int d = 0;
  uint32_t cka = k0a, ckb = k0b;
  int ce = jj;                 // current element end = count_so_far + jj
  int runm = -1000;            // cummax of ends (below any warmup value)
  uint32_t cur = 0;            // current 32-step spike word

  // Warmup (h=1): rebuild cummax carry; no recording. Lanes stop exactly at
  // jj==0 with fresh element state (advance happens only on fin).
  if (h) {
    while (__any(jj < 0)) {
      if (jj < 0) DRAW(false)
      if (jj < 0) DRAW(false)
    }
  }

  // Main: 250 steps, 2 draws per ballot.
  while (__any(jj < HALF)) {
    if (jj < HALF) DRAW(true)
    if (jj < HALF) DRAW(true)
  }
  __syncthreads();

  // ---- coalesced unpack: thread t stores original job t (pixel pixBase+t) ----
  uint32_t off = (uint32_t)jstart * (uint32_t)N + (uint32_t)(pixBase + tid);
  for (int w = 0; w < 8; ++w) {
    const uint32_t word = xbuf[tid * XPITCH + w];
    const int nb = (w < 7) ? 32 : (HALF - 7 * 32);   // 26 bits in last word
    #pragma unroll 1
    for (int t2 = 0; t2 < nb; ++t2) {
      out[off] = (int)((word >> t2) & 1u);
      off += (uint32_t)N;
    }
  }
}

extern "C" void kernel_launch(void* const* d_in, const int* in_sizes, int n_in,
                              void* d_out, int out_size, void* d_ws, size_t ws_size,
                              hipStream_t stream) {
  const float* img = (const float*)d_in[0];
  int* out = (int*)d_out;
  const int N = in_sizes[0];  // 262144 (multiple of BLOCK)

  // Host-side subkey chain: rng = (0, 42); partitionable fold-like split.
  Subkeys sk;
  uint32_t r0 = 0u, r1 = 42u;
  for (int d = 0; d < NKEYS; ++d) {
    uint32_t s0, s1, n0, n1;
    tf2x32(r0, r1, 0u, 1u, s0, s1);  // subkey for draw d
    tf2x32(r0, r1, 0u, 0u, n0, n1);  // next rng
    sk.a[d] = s0; sk.b[d] = s1;
    r0 = n0; r1 = n1;
  }

  dim3 block(BLOCK);
  dim3 grid(2 * (N / BLOCK));
  hipLaunchKernelGGL(CustomPoisson_12292196401945_kernel, grid, block, 0, stream,
                     img, out, sk, N);
}

// Round 11
// 639.011 us; speedup vs baseline: 1.5842x; 1.0995x over previous
//
#include <hip/hip_runtime.h>
#include <stdint.h>

// Poisson spike encoding, bit-exact vs JAX CPU reference (verified rounds 2-9).
// Round 11: round-10 retry with host-pass-legal ROTL (the __host__-only
// fallback broke the host semantic pass). Guaranteed 1-op rotates via
// inline-asm v_alignbit_b32 on device; prefetch pointer replaces draw-index;
// lshl_or-friendly bit record. Structure = verified round 8/9.

#define TWIN 500
#define HALF 250
#define WARM 26          // cummax carry distance; P(count>=26) ~ 1e-18 dataset-wide
#define NKEYS 32         // subkey table; draws beyond ~15 unreachable
#define BLOCK 1024
#define XPITCH 9         // exchange pitch in words (conflict-spreading)

struct Subkeys {
  uint32_t a[NKEYS];
  uint32_t b[NKEYS];
};

__host__ __device__ __forceinline__ uint32_t rotl32_g(uint32_t x, uint32_t r) {
  return (x << r) | (x >> (32u - r));
}

#if defined(__HIP_DEVICE_COMPILE__)
// Guaranteed single v_alignbit_b32: rotl(x,r) == (x:x) >> (32-r).
#define ROTL(x, r)                                                          \
  ({ uint32_t _d;                                                           \
     asm("v_alignbit_b32 %0, %1, %1, %2" : "=v"(_d) : "v"(x), "n"(32 - (r))); \
     _d; })
#else
#define ROTL(x, r) rotl32_g((x), (r))   // host pass: semantic check only
#endif

__host__ void tf2x32_host(uint32_t k0, uint32_t k1,
                          uint32_t x0, uint32_t x1,
                          uint32_t& o0, uint32_t& o1) {
  const uint32_t ks2 = k0 ^ k1 ^ 0x1BD11BDAu;
  x0 += k0; x1 += k1;
#define TF_RND(r) { x0 += x1; x1 = rotl32_g(x1, (r)); x1 ^= x0; }
  TF_RND(13) TF_RND(15) TF_RND(26) TF_RND(6)
  x0 += k1;  x1 += ks2 + 1u;
  TF_RND(17) TF_RND(29) TF_RND(16) TF_RND(24)
  x0 += ks2; x1 += k0 + 2u;
  TF_RND(13) TF_RND(15) TF_RND(26) TF_RND(6)
  x0 += k0;  x1 += k1 + 3u;
  TF_RND(17) TF_RND(29) TF_RND(16) TF_RND(24)
  x0 += k1;  x1 += ks2 + 4u;
  TF_RND(13) TF_RND(15) TF_RND(26) TF_RND(6)
  x0 += ks2; x1 += k0 + 5u;
#undef TF_RND
  o0 = x0; o1 = x1;
}

// Cephes/Eigen plog<float>, FMA-contracted exactly as bit-verified in round 2.
__device__ __forceinline__ float cephes_logf(float u) {
  float x = fmaxf(u, __uint_as_float(0x00800000u));
  int emm0 = (int)(__float_as_uint(x) >> 23);
  x = __uint_as_float((__float_as_uint(x) & 0x807FFFFFu) | 0x3F000000u);
  float e = (float)(emm0 - 127) + 1.0f;
  const bool mask = x < 0.707106781186547524f;
  float tmp = mask ? x : 0.0f;
  x = x - 1.0f;
  e = e - (mask ? 1.0f : 0.0f);
  x = x + tmp;
  float z = x * x;
  float y = 7.0376836292E-2f;
  y = fmaf(y, x, -1.1514610310E-1f);
  y = fmaf(y, x,  1.1676998740E-1f);
  y = fmaf(y, x, -1.2420140846E-1f);
  y = fmaf(y, x,  1.4249322787E-1f);
  y = fmaf(y, x, -1.6668057665E-1f);
  y = fmaf(y, x,  2.0000714765E-1f);
  y = fmaf(y, x, -2.4999993993E-1f);
  y = fmaf(y, x,  3.3333331174E-1f);
  y = y * x;
  y = y * z;
  y = fmaf(e, -2.12194440e-4f, y);
  y = fmaf(z, -0.5f, y);
  x = x + y;
  x = fmaf(e, 0.693359375f, x);
  return x;
}

// One Knuth draw. fin == !alive (no draw cap: P(31 survivals) ~ 1e-34/elem).
// nkp points at the subkey for the NEXT draw if the element survives.
// DO_REC: record spike bit + flush word to LDS (idempotent, ungated).
#define DRAW(DO_REC)                                                        \
  {                                                                         \
    const uint2 nk = *nkp;                       /* prefetch next subkey */ \
    const uint32_t ks2 = cka ^ ckb ^ 0x1BD11BDAu;                           \
    uint32_t t0 = cka;                           /* x0 = 0 + k0 */          \
    uint32_t t1 = e_base + (uint32_t)jj + ckb;   /* x1 = e + k1 */          \
    t0 += t1; t1 = ROTL(t1, 13); t1 ^= t0;                                  \
    t0 += t1; t1 = ROTL(t1, 15); t1 ^= t0;                                  \
    t0 += t1; t1 = ROTL(t1, 26); t1 ^= t0;                                  \
    t0 += t1; t1 = ROTL(t1,  6); t1 ^= t0;                                  \
    t0 += ckb; t1 += ks2 + 1u;                                              \
    t0 += t1; t1 = ROTL(t1, 17); t1 ^= t0;                                  \
    t0 += t1; t1 = ROTL(t1, 29); t1 ^= t0;                                  \
    t0 += t1; t1 = ROTL(t1, 16); t1 ^= t0;                                  \
    t0 += t1; t1 = ROTL(t1, 24); t1 ^= t0;                                  \
    t0 += ks2; t1 += cka + 2u;                                              \
    t0 += t1; t1 = ROTL(t1, 13); t1 ^= t0;                                  \
    t0 += t1; t1 = ROTL(t1, 15); t1 ^= t0;                                  \
    t0 += t1; t1 = ROTL(t1, 26); t1 ^= t0;                                  \
    t0 += t1; t1 = ROTL(t1,  6); t1 ^= t0;                                  \
    t0 += cka; t1 += ckb + 3u;                                              \
    t0 += t1; t1 = ROTL(t1, 17); t1 ^= t0;                                  \
    t0 += t1; t1 = ROTL(t1, 29); t1 ^= t0;                                  \
    t0 += t1; t1 = ROTL(t1, 16); t1 ^= t0;                                  \
    t0 += t1; t1 = ROTL(t1, 24); t1 ^= t0;                                  \
    t0 += ckb; t1 += ks2 + 4u;                                              \
    t0 += t1; t1 = ROTL(t1, 13); t1 ^= t0;                                  \
    t0 += t1; t1 = ROTL(t1, 15); t1 ^= t0;                                  \
    t0 += t1; t1 = ROTL(t1, 26); t1 ^= t0;                                  \
    t0 += t1; t1 = ROTL(t1,  6); t1 ^= t0;                                  \
    t0 += ks2; t1 += cka + 5u;                                              \
    const uint32_t rb = t0 ^ t1;                                            \
    const float u = __uint_as_float((rb >> 9) | 0x3F800000u) - 1.0f;        \
    S += cephes_logf(u);                                                    \
    const bool alive = S > neg_lam;                                         \
    const int ce_eff = ce + (alive ? 1 : 0);     /* end if alive */         \
    runm = runm > ce_eff ? runm : ce_eff;        /* monotone, idempotent */ \
    if (DO_REC) {                                                           \
      cur |= ((uint32_t)(runm > jj)) << ((uint32_t)jj & 31u);               \
      xbuf[xw_base + ((uint32_t)jj >> 5)] = cur; /* idempotent rewrite */   \
    }                                                                       \
    S   = alive ? S : 0.0f;                                                 \
    nkp = alive ? (nkp + 1) : (lk + 1);                                     \
    cka = alive ? nk.x : k0a;                                               \
    ckb = alive ? nk.y : k0b;                                               \
    ce  = (alive ? ce : jj) + 1;                 /* new end (both cases) */ \
    jj  = alive ? jj : jj + 1;                                              \
    if (DO_REC) cur = (!alive && (((uint32_t)jj & 31u) == 0u)) ? 0u : cur;  \
  }

__global__ __attribute__((amdgpu_flat_work_group_size(BLOCK, BLOCK)))
void CustomPoisson_12292196401945_kernel(
    const float* __restrict__ img, int* __restrict__ out,
    Subkeys sk, int N) {
  __shared__ uint2 lk[NKEYS];
  __shared__ unsigned long long sbuf[BLOCK];       // sort records
  __shared__ uint32_t xbuf[BLOCK * XPITCH];        // spike-word exchange

  const int tid = threadIdx.x;
  if (tid < NKEYS) lk[tid] = make_uint2(sk.a[tid], sk.b[tid]);

  const int hb = N / BLOCK;                // blocks per half (256)
  const int b = blockIdx.x;
  const int h = (b >= hb) ? 1 : 0;         // block-uniform row half
  const int pixBase = (b - h * hb) * BLOCK;

  // ---- one-time bitonic sort of (lambda, local job id), ascending ----
  // Correctness needs only bijectivity (swap-based => guaranteed).
  {
    const float lam0 = img[pixBase + tid];
    sbuf[tid] = ((unsigned long long)__float_as_uint(lam0) << 32) | (uint32_t)tid;
  }
  __syncthreads();
  for (int ks = 2; ks <= BLOCK; ks <<= 1) {
    for (int js = ks >> 1; js > 0; js >>= 1) {
      const int p = tid ^ js;
      if (p > tid) {
        const bool up = ((tid & ks) == 0);
        const unsigned long long a = sbuf[tid], c = sbuf[p];
        const bool sw = up ? (a > c) : (a < c);
        if (sw) { sbuf[tid] = c; sbuf[p] = a; }
      }
      __syncthreads();
    }
  }
  const unsigned long long rec = sbuf[tid];        // rank tid's record
  const uint32_t orig = (uint32_t)rec;             // original local job id
  const float neg_lam = -__uint_as_float((uint32_t)(rec >> 32));

  const uint32_t k0a = sk.a[0], k0b = sk.b[0];     // uniform -> SGPRs
  const int jstart = h ? HALF : 0;
  const uint32_t e_base =
      (uint32_t)(pixBase + (int)orig) * TWIN + (uint32_t)jstart;
  const uint32_t xw_base = orig * XPITCH;

  // ---- streaming state (all step indices relative to jstart) ----
  int jj = h ? -WARM : 0;
  float S = 0.0f;
  uint32_t cka = k0a, ckb = k0b;
  const uint2* nkp = lk + 1;   // subkey for draw 1 (if element survives draw 0)
  int ce = jj;                 // current element end = count_so_far + jj
  int runm = -1000;            // cummax of ends (below any warmup value)
  uint32_t cur = 0;            // current 32-step spike word

  // Warmup (h=1): rebuild cummax carry; no recording. Lanes stop exactly at
  // jj==0 with fresh element state (advance happens only on death).
  if (h) {
    while (__any(jj < 0)) {
      if (jj < 0) DRAW(false)
      if (jj < 0) DRAW(false)
    }
  }

  // Main: 250 steps, 2 draws per ballot.
  while (__any(jj < HALF)) {
    if (jj < HALF) DRAW(true)
    if (jj < HALF) DRAW(true)
  }
  __syncthreads();

  // ---- coalesced unpack: thread t stores original job t (pixel pixBase+t) ----
  uint32_t off = (uint32_t)jstart * (uint32_t)N + (uint32_t)(pixBase + tid);
  for (int w = 0; w < 8; ++w) {
    const uint32_t word = xbuf[tid * XPITCH + w];
    const int nb = (w < 7) ? 32 : (HALF - 7 * 32);   // 26 bits in last word
    #pragma unroll 1
    for (int t2 = 0; t2 < nb; ++t2) {
      out[off] = (int)((word >> t2) & 1u);
      off += (uint32_t)N;
    }
  }
}

extern "C" void kernel_launch(void* const* d_in, const int* in_sizes, int n_in,
                              void* d_out, int out_size, void* d_ws, size_t ws_size,
                              hipStream_t stream) {
  const float* img = (const float*)d_in[0];
  int* out = (int*)d_out;
  const int N = in_sizes[0];  // 262144 (multiple of BLOCK)

  // Host-side subkey chain: rng = (0, 42); partitionable fold-like split.
  Subkeys sk;
  uint32_t r0 = 0u, r1 = 42u;
  for (int d = 0; d < NKEYS; ++d) {
    uint32_t s0, s1, n0, n1;
    tf2x32_host(r0, r1, 0u, 1u, s0, s1);  // subkey for draw d
    tf2x32_host(r0, r1, 0u, 0u, n0, n1);  // next rng
    sk.a[d] = s0; sk.b[d] = s1;
    r0 = n0; r1 = n1;
  }

  dim3 block(BLOCK);
  dim3 grid(2 * (N / BLOCK));
  hipLaunchKernelGGL(CustomPoisson_12292196401945_kernel, grid, block, 0, stream,
                     img, out, sk, N);
}

// Round 12
// 638.858 us; speedup vs baseline: 1.5846x; 1.0002x over previous
//
#include <hip/hip_runtime.h>
#include <stdint.h>

// Poisson spike encoding, bit-exact vs JAX CPU reference (verified rounds 2-11).
// Round 12: rank-indexed LDS exchange (conflict-free per-draw ds_write; the
// orig->rank inverse permutation moves scatter to 8 one-time reads) and
// 4 draws per ballot. Draw semantics byte-identical to round 11.

#define TWIN 500
#define HALF 250
#define WARM 26          // cummax carry distance; P(count>=26) ~ 1e-18 dataset-wide
#define NKEYS 32         // subkey table; draws beyond ~15 unreachable
#define BLOCK 1024
#define XPITCH 9         // exchange pitch in words; stride 9 -> 2 lanes/bank (free)

struct Subkeys {
  uint32_t a[NKEYS];
  uint32_t b[NKEYS];
};

__host__ __device__ __forceinline__ uint32_t rotl32_g(uint32_t x, uint32_t r) {
  return (x << r) | (x >> (32u - r));
}

#if defined(__HIP_DEVICE_COMPILE__)
// Guaranteed single v_alignbit_b32: rotl(x,r) == (x:x) >> (32-r).
#define ROTL(x, r)                                                          \
  ({ uint32_t _d;                                                           \
     asm("v_alignbit_b32 %0, %1, %1, %2" : "=v"(_d) : "v"(x), "n"(32 - (r))); \
     _d; })
#else
#define ROTL(x, r) rotl32_g((x), (r))   // host pass: semantic check only
#endif

__host__ void tf2x32_host(uint32_t k0, uint32_t k1,
                          uint32_t x0, uint32_t x1,
                          uint32_t& o0, uint32_t& o1) {
  const uint32_t ks2 = k0 ^ k1 ^ 0x1BD11BDAu;
  x0 += k0; x1 += k1;
#define TF_RND(r) { x0 += x1; x1 = rotl32_g(x1, (r)); x1 ^= x0; }
  TF_RND(13) TF_RND(15) TF_RND(26) TF_RND(6)
  x0 += k1;  x1 += ks2 + 1u;
  TF_RND(17) TF_RND(29) TF_RND(16) TF_RND(24)
  x0 += ks2; x1 += k0 + 2u;
  TF_RND(13) TF_RND(15) TF_RND(26) TF_RND(6)
  x0 += k0;  x1 += k1 + 3u;
  TF_RND(17) TF_RND(29) TF_RND(16) TF_RND(24)
  x0 += k1;  x1 += ks2 + 4u;
  TF_RND(13) TF_RND(15) TF_RND(26) TF_RND(6)
  x0 += ks2; x1 += k0 + 5u;
#undef TF_RND
  o0 = x0; o1 = x1;
}

// Cephes/Eigen plog<float>, FMA-contracted exactly as bit-verified in round 2.
__device__ __forceinline__ float cephes_logf(float u) {
  float x = fmaxf(u, __uint_as_float(0x00800000u));
  int emm0 = (int)(__float_as_uint(x) >> 23);
  x = __uint_as_float((__float_as_uint(x) & 0x807FFFFFu) | 0x3F000000u);
  float e = (float)(emm0 - 127) + 1.0f;
  const bool mask = x < 0.707106781186547524f;
  float tmp = mask ? x : 0.0f;
  x = x - 1.0f;
  e = e - (mask ? 1.0f : 0.0f);
  x = x + tmp;
  float z = x * x;
  float y = 7.0376836292E-2f;
  y = fmaf(y, x, -1.1514610310E-1f);
  y = fmaf(y, x,  1.1676998740E-1f);
  y = fmaf(y, x, -1.2420140846E-1f);
  y = fmaf(y, x,  1.4249322787E-1f);
  y = fmaf(y, x, -1.6668057665E-1f);
  y = fmaf(y, x,  2.0000714765E-1f);
  y = fmaf(y, x, -2.4999993993E-1f);
  y = fmaf(y, x,  3.3333331174E-1f);
  y = y * x;
  y = y * z;
  y = fmaf(e, -2.12194440e-4f, y);
  y = fmaf(z, -0.5f, y);
  x = x + y;
  x = fmaf(e, 0.693359375f, x);
  return x;
}

// One Knuth draw. fin == !alive (no draw cap: P(31 survivals) ~ 1e-34/elem).
// nkp points at the subkey for the NEXT draw if the element survives.
// DO_REC: record spike bit + flush word to LDS (idempotent, ungated).
#define DRAW(DO_REC)                                                        \
  {                                                                         \
    const uint2 nk = *nkp;                       /* prefetch next subkey */ \
    const uint32_t ks2 = cka ^ ckb ^ 0x1BD11BDAu;                           \
    uint32_t t0 = cka;                           /* x0 = 0 + k0 */          \
    uint32_t t1 = e_base + (uint32_t)jj + ckb;   /* x1 = e + k1 */          \
    t0 += t1; t1 = ROTL(t1, 13); t1 ^= t0;                                  \
    t0 += t1; t1 = ROTL(t1, 15); t1 ^= t0;                                  \
    t0 += t1; t1 = ROTL(t1, 26); t1 ^= t0;                                  \
    t0 += t1; t1 = ROTL(t1,  6); t1 ^= t0;                                  \
    t0 += ckb; t1 += ks2 + 1u;                                              \
    t0 += t1; t1 = ROTL(t1, 17); t1 ^= t0;                                  \
    t0 += t1; t1 = ROTL(t1, 29); t1 ^= t0;                                  \
    t0 += t1; t1 = ROTL(t1, 16); t1 ^= t0;                                  \
    t0 += t1; t1 = ROTL(t1, 24); t1 ^= t0;                                  \
    t0 += ks2; t1 += cka + 2u;                                              \
    t0 += t1; t1 = ROTL(t1, 13); t1 ^= t0;                                  \
    t0 += t1; t1 = ROTL(t1, 15); t1 ^= t0;                                  \
    t0 += t1; t1 = ROTL(t1, 26); t1 ^= t0;                                  \
    t0 += t1; t1 = ROTL(t1,  6); t1 ^= t0;                                  \
    t0 += cka; t1 += ckb + 3u;                                              \
    t0 += t1; t1 = ROTL(t1, 17); t1 ^= t0;                                  \
    t0 += t1; t1 = ROTL(t1, 29); t1 ^= t0;                                  \
    t0 += t1; t1 = ROTL(t1, 16); t1 ^= t0;                                  \
    t0 += t1; t1 = ROTL(t1, 24); t1 ^= t0;                                  \
    t0 += ckb; t1 += ks2 + 4u;                                              \
    t0 += t1; t1 = ROTL(t1, 13); t1 ^= t0;                                  \
    t0 += t1; t1 = ROTL(t1, 15); t1 ^= t0;                                  \
    t0 += t1; t1 = ROTL(t1, 26); t1 ^= t0;                                  \
    t0 += t1; t1 = ROTL(t1,  6); t1 ^= t0;                                  \
    t0 += ks2; t1 += cka + 5u;                                              \
    const uint32_t rb = t0 ^ t1;                                            \
    const float u = __uint_as_float((rb >> 9) | 0x3F800000u) - 1.0f;        \
    S += cephes_logf(u);                                                    \
    const bool alive = S > neg_lam;                                         \
    const int ce_eff = ce + (alive ? 1 : 0);     /* end if alive */         \
    runm = runm > ce_eff ? runm : ce_eff;        /* monotone, idempotent */ \
    if (DO_REC) {                                                           \
      cur |= ((uint32_t)(runm > jj)) << ((uint32_t)jj & 31u);               \
      xbuf[xw_base + ((uint32_t)jj >> 5)] = cur; /* idempotent rewrite */   \
    }                                                                       \
    S   = alive ? S : 0.0f;                                                 \
    nkp = alive ? (nkp + 1) : (lk + 1);                                     \
    cka = alive ? nk.x : k0a;                                               \
    ckb = alive ? nk.y : k0b;                                               \
    ce  = (alive ? ce : jj) + 1;                 /* new end (both cases) */ \
    jj  = alive ? jj : jj + 1;                                              \
    if (DO_REC) cur = (!alive && (((uint32_t)jj & 31u) == 0u)) ? 0u : cur;  \
  }

__global__ __attribute__((amdgpu_flat_work_group_size(BLOCK, BLOCK)))
void CustomPoisson_12292196401945_kernel(
    const float* __restrict__ img, int* __restrict__ out,
    Subkeys sk, int N) {
  __shared__ uint2 lk[NKEYS];
  __shared__ unsigned long long sbuf[BLOCK];       // sort records
  __shared__ uint32_t xbuf[BLOCK * XPITCH];        // spike-word exchange (by RANK)
  __shared__ uint32_t inv[BLOCK];                  // orig -> rank

  const int tid = threadIdx.x;
  if (tid < NKEYS) lk[tid] = make_uint2(sk.a[tid], sk.b[tid]);

  const int hb = N / BLOCK;                // blocks per half (256)
  const int b = blockIdx.x;
  const int h = (b >= hb) ? 1 : 0;         // block-uniform row half
  const int pixBase = (b - h * hb) * BLOCK;

  // ---- one-time bitonic sort of (lambda, local job id), ascending ----
  // Correctness needs only bijectivity (swap-based => guaranteed).
  {
    const float lam0 = img[pixBase + tid];
    sbuf[tid] = ((unsigned long long)__float_as_uint(lam0) << 32) | (uint32_t)tid;
  }
  __syncthreads();
  for (int ks = 2; ks <= BLOCK; ks <<= 1) {
    for (int js = ks >> 1; js > 0; js >>= 1) {
      const int p = tid ^ js;
      if (p > tid) {
        const bool up = ((tid & ks) == 0);
        const unsigned long long a = sbuf[tid], c = sbuf[p];
        const bool sw = up ? (a > c) : (a < c);
        if (sw) { sbuf[tid] = c; sbuf[p] = a; }
      }
      __syncthreads();
    }
  }
  const unsigned long long rec = sbuf[tid];        // rank tid's record
  const uint32_t orig = (uint32_t)rec;             // original local job id
  const float neg_lam = -__uint_as_float((uint32_t)(rec >> 32));
  inv[orig] = (uint32_t)tid;    // inverse permutation (read after main barrier)

  const uint32_t k0a = sk.a[0], k0b = sk.b[0];     // uniform -> SGPRs
  const int jstart = h ? HALF : 0;
  const uint32_t e_base =
      (uint32_t)(pixBase + (int)orig) * TWIN + (uint32_t)jstart;
  const uint32_t xw_base = (uint32_t)tid * XPITCH; // RANK-indexed: conflict-free

  // ---- streaming state (all step indices relative to jstart) ----
  int jj = h ? -WARM : 0;
  float S = 0.0f;
  uint32_t cka = k0a, ckb = k0b;
  const uint2* nkp = lk + 1;   // subkey for draw 1 (if element survives draw 0)
  int ce = jj;                 // current element end = count_so_far + jj
  int runm = -1000;            // cummax of ends (below any warmup value)
  uint32_t cur = 0;            // current 32-step spike word

  // Warmup (h=1): rebuild cummax carry; no recording. Lanes stop exactly at
  // jj==0 with fresh element state (advance happens only on death).
  if (h) {
    while (__any(jj < 0)) {
      if (jj < 0) DRAW(false)
      if (jj < 0) DRAW(false)
    }
  }

  // Main: 250 steps, 4 draws per ballot.
  while (__any(jj < HALF)) {
    if (jj < HALF) DRAW(true)
    if (jj < HALF) DRAW(true)
    if (jj < HALF) DRAW(true)
    if (jj < HALF) DRAW(true)
  }
  __syncthreads();

  // ---- coalesced unpack: thread t stores original job t (pixel pixBase+t) ----
  const uint32_t rank2 = inv[tid];                 // where job t's words live
  uint32_t off = (uint32_t)jstart * (uint32_t)N + (uint32_t)(pixBase + tid);
  for (int w = 0; w < 8; ++w) {
    const uint32_t word = xbuf[rank2 * XPITCH + (uint32_t)w];
    const int nb = (w < 7) ? 32 : (HALF - 7 * 32);   // 26 bits in last word
    #pragma unroll 1
    for (int t2 = 0; t2 < nb; ++t2) {
      out[off] = (int)((word >> t2) & 1u);
      off += (uint32_t)N;
    }
  }
}

extern "C" void kernel_launch(void* const* d_in, const int* in_sizes, int n_in,
                              void* d_out, int out_size, void* d_ws, size_t ws_size,
                              hipStream_t stream) {
  const float* img = (const float*)d_in[0];
  int* out = (int*)d_out;
  const int N = in_sizes[0];  // 262144 (multiple of BLOCK)

  // Host-side subkey chain: rng = (0, 42); partitionable fold-like split.
  Subkeys sk;
  uint32_t r0 = 0u, r1 = 42u;
  for (int d = 0; d < NKEYS; ++d) {
    uint32_t s0, s1, n0, n1;
    tf2x32_host(r0, r1, 0u, 1u, s0, s1);  // subkey for draw d
    tf2x32_host(r0, r1, 0u, 0u, n0, n1);  // next rng
    sk.a[d] = s0; sk.b[d] = s1;
    r0 = n0; r1 = n1;
  }

  dim3 block(BLOCK);
  dim3 grid(2 * (N / BLOCK));
  hipLaunchKernelGGL(CustomPoisson_12292196401945_kernel, grid, block, 0, stream,
                     img, out, sk, N);
}